// Round 16
// baseline (288.139 us; speedup 1.0000x reference)
//
#include <hip/hip_runtime.h>
#include <hip/hip_bf16.h>
#include <math.h>

// Problem constants
#define M_ 16
#define N_ 4096
#define D_ 128
#define P_ 8192
#define H_ 32

// q-projection tiling (launch 1)
#define NIC 32
#define ICH (N_/NIC)
#define NCB 16

// kv-projection tiling (inside k_main)
#define NIC_KV 8
#define ICH_KV (N_/NIC_KV)   // 512, staged 4 x 128

// Attention chunking
#define CHUNK 64
#define NCH (P_/CHUNK)    // 128 cache chunks
#define NCH1 (NCH+1)

// Workspace layout (float offsets)
#define QKV_SZ       (3*H_*M_*D_)                    // 196608
#define OPART_OFF    (QKV_SZ)
#define OPART_HALFSZ ((H_*NCH1*M_*D_)/2)             // 4227072 f32 slots (bf16)
#define PART_Q_OFF   (OPART_OFF)                     // aliases opart (dead first)
#define ML_OFF       (OPART_OFF + OPART_HALFSZ)
#define ML_SZ        (H_*NCH1*M_*2)                  // 132096
#define PART_KV_OFF  (ML_OFF + ML_SZ)                // 2*8*16*4096 = 1048576

// k_main grid: 4352 = 17*256; 1 of 17 is a kv-proj block
#define MAIN_BLOCKS 4352

// ---------------------------------------------------------------------------
// Kernel 1: q projection (mat 0 only). grid (NCB, NIC, 1), block 256.
// ---------------------------------------------------------------------------
__global__ __launch_bounds__(256) void k_proj(const float* __restrict__ X,
                                              const float* __restrict__ Wq,
                                              float* __restrict__ part) {
  const int cb = blockIdx.x, ic = blockIdx.y;
  const int t = threadIdx.x;
  const int j0 = cb * 256 + t;
  const int i0 = ic * ICH;

  __shared__ __align__(16) float XT[ICH][20];
  {
    const int i_l = t & 127, mh = t >> 7;
#pragma unroll
    for (int r = 0; r < 8; ++r)
      XT[i_l][mh * 8 + r] = X[(size_t)(mh * 8 + r) * N_ + i0 + i_l];
  }
  __syncthreads();

  float acc[16];
#pragma unroll
  for (int m = 0; m < 16; ++m) acc[m] = 0.f;

#pragma unroll 8
  for (int i = 0; i < ICH; ++i) {
    const float wv = __builtin_nontemporal_load(Wq + (size_t)(i0 + i) * N_ + j0);
    float xr[16];
    {
      float4 xv;
      xv = *reinterpret_cast<const float4*>(&XT[i][0]);
      xr[0] = xv.x; xr[1] = xv.y; xr[2] = xv.z; xr[3] = xv.w;
      xv = *reinterpret_cast<const float4*>(&XT[i][4]);
      xr[4] = xv.x; xr[5] = xv.y; xr[6] = xv.z; xr[7] = xv.w;
      xv = *reinterpret_cast<const float4*>(&XT[i][8]);
      xr[8] = xv.x; xr[9] = xv.y; xr[10] = xv.z; xr[11] = xv.w;
      xv = *reinterpret_cast<const float4*>(&XT[i][12]);
      xr[12] = xv.x; xr[13] = xv.y; xr[14] = xv.z; xr[15] = xv.w;
    }
#pragma unroll
    for (int m = 0; m < 16; ++m) acc[m] = fmaf(xr[m], wv, acc[m]);
  }

#pragma unroll
  for (int m = 0; m < 16; ++m)
    __builtin_nontemporal_store(acc[m], part + (size_t)(ic * M_ + m) * N_ + j0);
}

// ---------------------------------------------------------------------------
// Kernel 2: reduce nch partials, RMS-norm (mat<2), relayout.
// grid (16, 16, nz); mat = mat_base + blockIdx.z; src indexed by local mat.
// ---------------------------------------------------------------------------
__global__ __launch_bounds__(256) void k_reduce(const float* __restrict__ src,
                                                float* __restrict__ qkv,
                                                int nch, int mat_base) {
  const int matL = blockIdx.z, m = blockIdx.y, nc = blockIdx.x;
  const int mat = mat_base + matL;
  const int t = threadIdx.x;
  const int n = nc * 256 + t;

  float s = 0.f;
  for (int ic = 0; ic < nch; ++ic)
    s += __builtin_nontemporal_load(src + (size_t)((matL * nch + ic) * M_ + m) * N_ + n);

  float ss = s * s;
#pragma unroll
  for (int off = 1; off < 64; off <<= 1) ss += __shfl_xor(ss, off);
  __shared__ float wsum[4];
  const int wave = t >> 6, lane = t & 63;
  if (lane == 0) wsum[wave] = ss;
  __syncthreads();
  const int half = t >> 7;
  const float tot = wsum[half * 2] + wsum[half * 2 + 1];
  const float scale = (mat < 2) ? rsqrtf(tot * (1.0f / 128.0f)) : 1.0f;

  const int h = n >> 7, d = n & 127;
  qkv[(size_t)((mat * H_ + h) * M_ + m) * D_ + d] = s * scale;
}

// ---------------------------------------------------------------------------
// fold8: reduce a[0..7] over the 8 dq-lanes (lane bits 0..2).
// ---------------------------------------------------------------------------
__device__ __forceinline__ float fold8(float a[8], int dq) {
#pragma unroll
  for (int i = 0; i < 4; ++i) {
    const float send = (dq & 4) ? a[i] : a[i + 4];
    const float recv = __shfl_xor(send, 4);
    a[i] = ((dq & 4) ? a[i + 4] : a[i]) + recv;
  }
#pragma unroll
  for (int i = 0; i < 2; ++i) {
    const float send = (dq & 2) ? a[i] : a[i + 2];
    const float recv = __shfl_xor(send, 2);
    a[i] = ((dq & 2) ? a[i + 2] : a[i]) + recv;
  }
  {
    const float send = (dq & 1) ? a[0] : a[1];
    const float recv = __shfl_xor(send, 1);
    a[0] = ((dq & 1) ? a[1] : a[0]) + recv;
  }
  return a[0];
}

__device__ __forceinline__ unsigned pk2(float a, float b) {
  __hip_bfloat16 ha = __float2bfloat16(a), hb = __float2bfloat16(b);
  const unsigned short ua = *reinterpret_cast<unsigned short*>(&ha);
  const unsigned short ub = *reinterpret_cast<unsigned short*>(&hb);
  return (unsigned)ua | ((unsigned)ub << 16);
}

// ---------------------------------------------------------------------------
// Kernel 3: FUSED attn (4096 blocks) + kv-projection (256 blocks).
// Rationale: 8 attn structures all plateau at ~105us with demand-BW ~2.8TB/s
// while proj-style streams hit ~6TB/s; attn's latency bubbles leave memory
// slots idle -> fill them with the W_k/W_v projection stream (134 MB).
// Attn role: r15 arithmetic + K AND V double-buffered one batch ahead
// (prologue holds 2 batches ~12KB/wave in flight; FIFO vmcnt keeps the
// prefetch outstanding while current batch computes).
// ---------------------------------------------------------------------------
__global__ __attribute__((amdgpu_waves_per_eu(2, 8)))
__launch_bounds__(256) void k_main(const float* __restrict__ X,
                                   const float* __restrict__ Wk,
                                   const float* __restrict__ Wv,
                                   const float* __restrict__ cacheK,
                                   const float* __restrict__ cacheV,
                                   const float* __restrict__ qkv,
                                   float* __restrict__ part_kv,
                                   __hip_bfloat16* __restrict__ opart,
                                   float* __restrict__ ml) {
  __shared__ __align__(16) float shmem[4672];  // union: attn 18688B / proj XT 10240B
  const int bid = blockIdx.x;
  const int t = threadIdx.x;
  const bool is_proj = (bid % 17) == 16;

  if (is_proj) {
    // ---- kv-projection role: 256 blocks, ICH_KV=512 staged 4x128 ----
    const int proj_id = bid / 17;            // 0..255
    const int matL = proj_id >> 7;           // 0: Wk, 1: Wv
    const int ic = (proj_id >> 4) & 7;
    const int cb = proj_id & 15;
    const float* __restrict__ W = matL ? Wv : Wk;
    const int j0 = cb * 256 + t;
    float (*XT)[20] = reinterpret_cast<float (*)[20]>(shmem);  // [128][20]

    float acc[16];
#pragma unroll
    for (int m = 0; m < 16; ++m) acc[m] = 0.f;

    for (int s4 = 0; s4 < 4; ++s4) {
      const int i0 = ic * ICH_KV + s4 * 128;
      __syncthreads();   // previous stage consumed
      {
        const int i_l = t & 127, mh = t >> 7;
#pragma unroll
        for (int r = 0; r < 8; ++r)
          XT[i_l][mh * 8 + r] = X[(size_t)(mh * 8 + r) * N_ + i0 + i_l];
      }
      __syncthreads();
#pragma unroll 8
      for (int i = 0; i < 128; ++i) {
        const float wv = __builtin_nontemporal_load(W + (size_t)(i0 + i) * N_ + j0);
        float xr[16];
        {
          float4 xv;
          xv = *reinterpret_cast<const float4*>(&XT[i][0]);
          xr[0] = xv.x; xr[1] = xv.y; xr[2] = xv.z; xr[3] = xv.w;
          xv = *reinterpret_cast<const float4*>(&XT[i][4]);
          xr[4] = xv.x; xr[5] = xv.y; xr[6] = xv.z; xr[7] = xv.w;
          xv = *reinterpret_cast<const float4*>(&XT[i][8]);
          xr[8] = xv.x; xr[9] = xv.y; xr[10] = xv.z; xr[11] = xv.w;
          xv = *reinterpret_cast<const float4*>(&XT[i][12]);
          xr[12] = xv.x; xr[13] = xv.y; xr[14] = xv.z; xr[15] = xv.w;
        }
#pragma unroll
        for (int m = 0; m < 16; ++m) acc[m] = fmaf(xr[m], wv, acc[m]);
      }
    }
#pragma unroll
    for (int m = 0; m < 16; ++m)
      __builtin_nontemporal_store(acc[m],
          part_kv + (size_t)((matL * NIC_KV + ic) * M_ + m) * N_ + j0);
    return;
  }

  // ---- attention role: 4096 blocks, c in [0,128), valid = 64 always ----
  const int attn_id = (bid / 17) * 16 + (bid % 17);
  const int h = attn_id >> 7, c = attn_id & 127;
  const int wave = t >> 6, lane = t & 63;
  const float* __restrict__ Ksrc = cacheK + ((size_t)h * P_ + (size_t)c * CHUNK) * D_;
  const float* __restrict__ Vsrc = cacheV + ((size_t)h * P_ + (size_t)c * CHUNK) * D_;

  float* qs = shmem;                    // [16][128] = 2048 floats
  float* wxp = shmem + 4096 + wave * 128;
  float* mlx = shmem + 4608;            // [4][8][2] = 64 floats

  // stage q
  {
    const float4* src = reinterpret_cast<const float4*>(qkv + (size_t)(h * M_) * D_);
    reinterpret_cast<float4*>(qs)[t] = src[t];
    reinterpret_cast<float4*>(qs)[t + 256] = src[t + 256];
  }
  __syncthreads();

  const int pg = lane >> 3, dq = lane & 7;
  const int dl = lane * 2;
  const int rg = wave >> 1, mbase = (wave & 1) * 8;
  const int rbase = rg * 32;

  float mrun = -3.0e38f, lrun = 0.f;
  float2 o[8];
#pragma unroll
  for (int mi = 0; mi < 8; ++mi) o[mi] = make_float2(0.f, 0.f);

  float4 kkA[4], kkB[4];
  float2 vvA[8], vvB[8];

  auto kload = [&](float4 (&kk)[4], int r0) {
    const float* ka = Ksrc + (size_t)(r0 + pg) * D_ + dq * 4;
    kk[0] = *reinterpret_cast<const float4*>(ka);
    kk[1] = *reinterpret_cast<const float4*>(ka + 32);
    kk[2] = *reinterpret_cast<const float4*>(ka + 64);
    kk[3] = *reinterpret_cast<const float4*>(ka + 96);
  };
  auto vload = [&](float2 (&vv)[8], int r0) {
#pragma unroll
    for (int j = 0; j < 8; ++j)
      vv[j] = *reinterpret_cast<const float2*>(Vsrc + (size_t)(r0 + j) * D_ + dl);
  };
  auto body = [&](float4 (&kk)[4], float2 (&vv)[8]) {
    float a[8];
#pragma unroll
    for (int mi = 0; mi < 8; ++mi) {
      const float* qrow = qs + (mbase + mi) * D_ + dq * 4;
      const float4 q0 = *reinterpret_cast<const float4*>(qrow);
      const float4 q1 = *reinterpret_cast<const float4*>(qrow + 32);
      const float4 q2 = *reinterpret_cast<const float4*>(qrow + 64);
      const float4 q3 = *reinterpret_cast<const float4*>(qrow + 96);
      float s;
      s = q0.x * kk[0].x;
      s = fmaf(q0.y, kk[0].y, s); s = fmaf(q0.z, kk[0].z, s); s = fmaf(q0.w, kk[0].w, s);
      s = fmaf(q1.x, kk[1].x, s); s = fmaf(q1.y, kk[1].y, s);
      s = fmaf(q1.z, kk[1].z, s); s = fmaf(q1.w, kk[1].w, s);
      s = fmaf(q2.x, kk[2].x, s); s = fmaf(q2.y, kk[2].y, s);
      s = fmaf(q2.z, kk[2].z, s); s = fmaf(q2.w, kk[2].w, s);
      s = fmaf(q3.x, kk[3].x, s); s = fmaf(q3.y, kk[3].y, s);
      s = fmaf(q3.z, kk[3].z, s); s = fmaf(q3.w, kk[3].w, s);
      a[mi] = s;
    }
    const float sA = fold8(a, dq);
    float tmax = sA;
    tmax = fmaxf(tmax, __shfl_xor(tmax, 8));
    tmax = fmaxf(tmax, __shfl_xor(tmax, 16));
    tmax = fmaxf(tmax, __shfl_xor(tmax, 32));
    const float mnew = fmaxf(mrun, tmax);
    const float fc = __expf(mrun - mnew);
    mrun = mnew;
    const float wA = __expf(sA - mnew);
    float rs = wA;
    rs += __shfl_xor(rs, 8); rs += __shfl_xor(rs, 16); rs += __shfl_xor(rs, 32);
    lrun = lrun * fc + rs;
    wxp[pg * 8 + dq] = wA;
#pragma unroll
    for (int mi = 0; mi < 8; ++mi) {
      const float fcm = __shfl(fc, (lane & 56) | mi);
      o[mi].x *= fcm; o[mi].y *= fcm;
    }
#pragma unroll
    for (int j = 0; j < 8; ++j) {
      const float4 w0 = *reinterpret_cast<const float4*>(&wxp[j * 8]);
      const float4 w1 = *reinterpret_cast<const float4*>(&wxp[j * 8 + 4]);
      const float2 v = vv[j];
#define PVM(i, wc) o[i].x = fmaf(wc, v.x, o[i].x); o[i].y = fmaf(wc, v.y, o[i].y);
      PVM(0, w0.x) PVM(1, w0.y) PVM(2, w0.z) PVM(3, w0.w)
      PVM(4, w1.x) PVM(5, w1.y) PVM(6, w1.z) PVM(7, w1.w)
#undef PVM
    }
  };

  // prologue: two batches in flight
  kload(kkA, rbase);      vload(vvA, rbase);
  kload(kkB, rbase + 8);  vload(vvB, rbase + 8);
  // b0 (A), prefetch A<-rows+16
  body(kkA, vvA);
  kload(kkA, rbase + 16); vload(vvA, rbase + 16);
  // b1 (B), prefetch B<-rows+24
  body(kkB, vvB);
  kload(kkB, rbase + 24); vload(vvB, rbase + 24);
  // b2 (A), b3 (B)
  body(kkA, vvA);
  body(kkB, vvB);

  // ---- merge the 4 wave-partials ----
  __syncthreads();
  float* obuf = shmem;  // [4 waves][8 m][128 d]
#pragma unroll
  for (int mi = 0; mi < 8; ++mi)
    *reinterpret_cast<float2*>(&obuf[wave * 1024 + mi * 128 + dl]) = o[mi];
  if (lane < 8) { mlx[(wave * 8 + lane) * 2] = mrun; mlx[(wave * 8 + lane) * 2 + 1] = lrun; }
  __syncthreads();

  {
    const int mm = t >> 4, seg = t & 15;
    const int mh = mm >> 3, mi = mm & 7;
    const float m0v = mlx[(mh * 8 + mi) * 2], m1v = mlx[((2 + mh) * 8 + mi) * 2];
    const float mstar = fmaxf(m0v, m1v);
    const float e0 = __expf(m0v - mstar), e1 = __expf(m1v - mstar);
    const float T = mlx[(mh * 8 + mi) * 2 + 1] * e0 + mlx[((2 + mh) * 8 + mi) * 2 + 1] * e1;
    const float4 a0 = *reinterpret_cast<const float4*>(&obuf[mh * 1024 + mi * 128 + seg * 8]);
    const float4 a1 = *reinterpret_cast<const float4*>(&obuf[mh * 1024 + mi * 128 + seg * 8 + 4]);
    const float4 b0 = *reinterpret_cast<const float4*>(&obuf[(2 + mh) * 1024 + mi * 128 + seg * 8]);
    const float4 b1 = *reinterpret_cast<const float4*>(&obuf[(2 + mh) * 1024 + mi * 128 + seg * 8 + 4]);
    float r0 = e0 * a0.x + e1 * b0.x, r1 = e0 * a0.y + e1 * b0.y;
    float r2 = e0 * a0.z + e1 * b0.z, r3 = e0 * a0.w + e1 * b0.w;
    float r4 = e0 * a1.x + e1 * b1.x, r5 = e0 * a1.y + e1 * b1.y;
    float r6 = e0 * a1.z + e1 * b1.z, r7 = e0 * a1.w + e1 * b1.w;
    uint4 pk;
    pk.x = pk2(r0, r1); pk.y = pk2(r2, r3); pk.z = pk2(r4, r5); pk.w = pk2(r6, r7);
    const size_t base = ((size_t)(h * NCH1 + c) * M_ + mm) * D_ + seg * 8;
    *reinterpret_cast<uint4*>(opart + base) = pk;
    if (seg == 0) {
      ml[((size_t)(h * NCH1 + c) * M_ + mm) * 2 + 0] = mstar;
      ml[((size_t)(h * NCH1 + c) * M_ + mm) * 2 + 1] = T;
    }
  }
}

// ---------------------------------------------------------------------------
// Kernel 3b: tail chunk (the 16 appended k_norm/v rows). grid (1, H_).
// ---------------------------------------------------------------------------
__global__ __attribute__((amdgpu_waves_per_eu(2, 8)))
__launch_bounds__(256) void k_attn_tail(const float* __restrict__ qkv,
                                        __hip_bfloat16* __restrict__ opart,
                                        float* __restrict__ ml) {
  const int h = blockIdx.y;
  const int c = NCH;
  const int t = threadIdx.x;
  const int wave = t >> 6, lane = t & 63;
  const int valid = M_;
  const float* __restrict__ Ksrc = qkv + (size_t)((1 * H_ + h) * M_) * D_;
  const float* __restrict__ Vsrc = qkv + (size_t)((2 * H_ + h) * M_) * D_;

  __shared__ __align__(16) float smem[4096];
  __shared__ __align__(16) float wx[4 * 128];
  __shared__ __align__(16) float mlx[4][8][2];
  float* qs = smem;
  float* wxp = wx + wave * 128;

  {
    const float4* src = reinterpret_cast<const float4*>(qkv + (size_t)(h * M_) * D_);
    reinterpret_cast<float4*>(qs)[t] = src[t];
    reinterpret_cast<float4*>(qs)[t + 256] = src[t + 256];
  }
  __syncthreads();

  const int pg = lane >> 3, dq = lane & 7;
  const int dl = lane * 2;
  const int rg = wave >> 1, mbase = (wave & 1) * 8;
  const int rbase = rg * 32;
  int rc = valid - rbase; rc = (rc < 0) ? 0 : rc;
  const int nb = rc >> 3;   // 2 for waves 0-1, 0 for waves 2-3

  float mrun = -3.0e38f, lrun = 0.f;
  float2 o[8];
#pragma unroll
  for (int mi = 0; mi < 8; ++mi) o[mi] = make_float2(0.f, 0.f);

#pragma unroll 1
  for (int b = 0; b < nb; ++b) {
    const int r0 = rbase + b * 8;
    float4 kk0, kk1, kk2, kk3;
    {
      const float* ka = Ksrc + (size_t)(r0 + pg) * D_ + dq * 4;
      kk0 = *reinterpret_cast<const float4*>(ka);
      kk1 = *reinterpret_cast<const float4*>(ka + 32);
      kk2 = *reinterpret_cast<const float4*>(ka + 64);
      kk3 = *reinterpret_cast<const float4*>(ka + 96);
    }
    float2 vv[8];
#pragma unroll
    for (int j = 0; j < 8; ++j)
      vv[j] = *reinterpret_cast<const float2*>(Vsrc + (size_t)(r0 + j) * D_ + dl);

    float a[8];
#pragma unroll
    for (int mi = 0; mi < 8; ++mi) {
      const float* qrow = qs + (mbase + mi) * D_ + dq * 4;
      const float4 q0 = *reinterpret_cast<const float4*>(qrow);
      const float4 q1 = *reinterpret_cast<const float4*>(qrow + 32);
      const float4 q2 = *reinterpret_cast<const float4*>(qrow + 64);
      const float4 q3 = *reinterpret_cast<const float4*>(qrow + 96);
      float s;
      s = q0.x * kk0.x;
      s = fmaf(q0.y, kk0.y, s); s = fmaf(q0.z, kk0.z, s); s = fmaf(q0.w, kk0.w, s);
      s = fmaf(q1.x, kk1.x, s); s = fmaf(q1.y, kk1.y, s);
      s = fmaf(q1.z, kk1.z, s); s = fmaf(q1.w, kk1.w, s);
      s = fmaf(q2.x, kk2.x, s); s = fmaf(q2.y, kk2.y, s);
      s = fmaf(q2.z, kk2.z, s); s = fmaf(q2.w, kk2.w, s);
      s = fmaf(q3.x, kk3.x, s); s = fmaf(q3.y, kk3.y, s);
      s = fmaf(q3.z, kk3.z, s); s = fmaf(q3.w, kk3.w, s);
      a[mi] = s;
    }
    const float sA = fold8(a, dq);
    float tmax = sA;
    tmax = fmaxf(tmax, __shfl_xor(tmax, 8));
    tmax = fmaxf(tmax, __shfl_xor(tmax, 16));
    tmax = fmaxf(tmax, __shfl_xor(tmax, 32));
    const float mnew = fmaxf(mrun, tmax);
    const float fc = __expf(mrun - mnew);
    mrun = mnew;
    const float wA = __expf(sA - mnew);
    float rs = wA;
    rs += __shfl_xor(rs, 8); rs += __shfl_xor(rs, 16); rs += __shfl_xor(rs, 32);
    lrun = lrun * fc + rs;
    wxp[pg * 8 + dq] = wA;
#pragma unroll
    for (int mi = 0; mi < 8; ++mi) {
      const float fcm = __shfl(fc, (lane & 56) | mi);
      o[mi].x *= fcm; o[mi].y *= fcm;
    }
#pragma unroll
    for (int j = 0; j < 8; ++j) {
      const float4 w0 = *reinterpret_cast<const float4*>(&wxp[j * 8]);
      const float4 w1 = *reinterpret_cast<const float4*>(&wxp[j * 8 + 4]);
      const float2 v = vv[j];
#define PVM(i, wc) o[i].x = fmaf(wc, v.x, o[i].x); o[i].y = fmaf(wc, v.y, o[i].y);
      PVM(0, w0.x) PVM(1, w0.y) PVM(2, w0.z) PVM(3, w0.w)
      PVM(4, w1.x) PVM(5, w1.y) PVM(6, w1.z) PVM(7, w1.w)
#undef PVM
    }
  }

  __syncthreads();
  float* obuf = smem;
#pragma unroll
  for (int mi = 0; mi < 8; ++mi)
    *reinterpret_cast<float2*>(&obuf[wave * 1024 + mi * 128 + dl]) = o[mi];
  if (lane < 8) { mlx[wave][lane][0] = mrun; mlx[wave][lane][1] = lrun; }
  __syncthreads();

  {
    const int mm = t >> 4, seg = t & 15;
    const int mh = mm >> 3, mi = mm & 7;
    const float m0v = mlx[mh][mi][0], m1v = mlx[2 + mh][mi][0];
    const float mstar = fmaxf(m0v, m1v);
    const float e0 = __expf(m0v - mstar), e1 = __expf(m1v - mstar);
    const float T = mlx[mh][mi][1] * e0 + mlx[2 + mh][mi][1] * e1;
    const float4 a0 = *reinterpret_cast<const float4*>(&obuf[mh * 1024 + mi * 128 + seg * 8]);
    const float4 a1 = *reinterpret_cast<const float4*>(&obuf[mh * 1024 + mi * 128 + seg * 8 + 4]);
    const float4 b0 = *reinterpret_cast<const float4*>(&obuf[(2 + mh) * 1024 + mi * 128 + seg * 8]);
    const float4 b1 = *reinterpret_cast<const float4*>(&obuf[(2 + mh) * 1024 + mi * 128 + seg * 8 + 4]);
    float r0 = e0 * a0.x + e1 * b0.x, r1 = e0 * a0.y + e1 * b0.y;
    float r2 = e0 * a0.z + e1 * b0.z, r3 = e0 * a0.w + e1 * b0.w;
    float r4 = e0 * a1.x + e1 * b1.x, r5 = e0 * a1.y + e1 * b1.y;
    float r6 = e0 * a1.z + e1 * b1.z, r7 = e0 * a1.w + e1 * b1.w;
    uint4 pk;
    pk.x = pk2(r0, r1); pk.y = pk2(r2, r3); pk.z = pk2(r4, r5); pk.w = pk2(r6, r7);
    const size_t base = ((size_t)(h * NCH1 + c) * M_ + mm) * D_ + seg * 8;
    *reinterpret_cast<uint4*>(opart + base) = pk;
    if (seg == 0) {
      ml[((size_t)(h * NCH1 + c) * M_ + mm) * 2 + 0] = mstar;
      ml[((size_t)(h * NCH1 + c) * M_ + mm) * 2 + 1] = T;
    }
  }
}

// ---------------------------------------------------------------------------
// Kernel 4: combine 129 chunk partials per (h, m). grid (M_, H_), block 128.
// ---------------------------------------------------------------------------
__global__ __launch_bounds__(128) void k_comb(const __hip_bfloat16* __restrict__ opart,
                                              const float* __restrict__ ml,
                                              float* __restrict__ out) {
  const int m = blockIdx.x, h = blockIdx.y, t = threadIdx.x;
  __shared__ float Ms[NCH1], Ls[NCH1];
  for (int i = t; i < NCH1; i += 128) {
    Ms[i] = ml[((size_t)(h * NCH1 + i) * M_ + m) * 2 + 0];
    Ls[i] = ml[((size_t)(h * NCH1 + i) * M_ + m) * 2 + 1];
  }
  __syncthreads();
  float gM = -3.0e38f;
#pragma unroll 8
  for (int c2 = 0; c2 < NCH1; ++c2) gM = fmaxf(gM, Ms[c2]);

  const __hip_bfloat16* __restrict__ ob =
      opart + (size_t)h * NCH1 * M_ * D_ + (size_t)m * D_ + t;
  float T = 0.f, o0 = 0.f, o1 = 0.f, o2 = 0.f, o3 = 0.f;
#pragma unroll 4
  for (int c2 = 0; c2 < NCH1 - 1; c2 += 4) {
    const float f0 = __expf(Ms[c2 + 0] - gM);
    const float f1 = __expf(Ms[c2 + 1] - gM);
    const float f2 = __expf(Ms[c2 + 2] - gM);
    const float f3 = __expf(Ms[c2 + 3] - gM);
    T = fmaf(Ls[c2 + 0], f0, T); T = fmaf(Ls[c2 + 1], f1, T);
    T = fmaf(Ls[c2 + 2], f2, T); T = fmaf(Ls[c2 + 3], f3, T);
    o0 = fmaf(__bfloat162float(ob[(size_t)(c2 + 0) * M_ * D_]), f0, o0);
    o1 = fmaf(__bfloat162float(ob[(size_t)(c2 + 1) * M_ * D_]), f1, o1);
    o2 = fmaf(__bfloat162float(ob[(size_t)(c2 + 2) * M_ * D_]), f2, o2);
    o3 = fmaf(__bfloat162float(ob[(size_t)(c2 + 3) * M_ * D_]), f3, o3);
  }
  {
    const int c2 = NCH1 - 1;
    const float f = __expf(Ms[c2] - gM);
    T = fmaf(Ls[c2], f, T);
    o0 = fmaf(__bfloat162float(ob[(size_t)c2 * M_ * D_]), f, o0);
  }
  out[(size_t)m * N_ + h * D_ + t] = (o0 + o1 + o2 + o3) / T;
}

// ---------------------------------------------------------------------------
extern "C" void kernel_launch(void* const* d_in, const int* in_sizes, int n_in,
                              void* d_out, int out_size, void* d_ws, size_t ws_size,
                              hipStream_t stream) {
  const float* X  = (const float*)d_in[0];
  const float* Wq = (const float*)d_in[1];
  const float* Wk = (const float*)d_in[2];
  const float* Wv = (const float*)d_in[3];
  const float* cK = (const float*)d_in[4];
  const float* cV = (const float*)d_in[5];
  float* ws     = (float*)d_ws;
  float* qkv    = ws;
  float* part_q = ws + PART_Q_OFF;     // aliases opart region (dead before k_main)
  __hip_bfloat16* opart = (__hip_bfloat16*)(ws + OPART_OFF);
  float* mlbuf  = ws + ML_OFF;
  float* part_kv = ws + PART_KV_OFF;
  float* out    = (float*)d_out;

  hipLaunchKernelGGL(k_proj,      dim3(NCB, NIC, 1), dim3(256), 0, stream, X, Wq, part_q);
  hipLaunchKernelGGL(k_reduce,    dim3(16, M_, 1),   dim3(256), 0, stream, part_q, qkv, NIC, 0);
  hipLaunchKernelGGL(k_main,      dim3(MAIN_BLOCKS), dim3(256), 0, stream,
                     X, Wk, Wv, cK, cV, qkv, part_kv, opart, mlbuf);
  hipLaunchKernelGGL(k_reduce,    dim3(16, M_, 2),   dim3(256), 0, stream, part_kv, qkv, NIC_KV, 1);
  hipLaunchKernelGGL(k_attn_tail, dim3(1, H_),       dim3(256), 0, stream, qkv, opart, mlbuf);
  hipLaunchKernelGGL(k_comb,      dim3(M_, H_),      dim3(128), 0, stream, opart, mlbuf, out);
}

// Round 17
// 162.445 us; speedup vs baseline: 1.7738x; 1.7738x over previous
//
#include <hip/hip_runtime.h>
#include <hip/hip_bf16.h>
#include <math.h>

// Problem constants
#define M_ 16
#define N_ 4096
#define D_ 128
#define P_ 8192
#define H_ 32

// Projection tiling
#define NIC 32
#define ICH (N_/NIC)
#define NCB 16            // 256-column blocks, 1 col/thread

// Attention chunking
#define CHUNK 64
#define NCH (P_/CHUNK)    // 128 cache chunks
#define NCH1 (NCH+1)      // +1 for the 16 appended rows

// Workspace layout (float offsets). opart is bf16.
#define QKV_SZ       (3*H_*M_*D_)
#define PART_OFF     (QKV_SZ)
#define OPART_OFF    (QKV_SZ)
#define OPART_HALFSZ ((H_*NCH1*M_*D_)/2)
#define ML_OFF       (OPART_OFF + OPART_HALFSZ)

// ---------------------------------------------------------------------------
// Kernel 1: partial QKV projection. grid (NCB, NIC, 3), block 256. (as r14)
// ---------------------------------------------------------------------------
__global__ __launch_bounds__(256) void k_proj(const float* __restrict__ X,
                                              const float* __restrict__ Wq,
                                              const float* __restrict__ Wk,
                                              const float* __restrict__ Wv,
                                              float* __restrict__ part) {
  const int mat = blockIdx.z;
  const float* __restrict__ W = (mat == 0) ? Wq : ((mat == 1) ? Wk : Wv);
  const int cb = blockIdx.x, ic = blockIdx.y;
  const int t = threadIdx.x;
  const int j0 = cb * 256 + t;
  const int i0 = ic * ICH;

  __shared__ __align__(16) float XT[ICH][20];

  {
    const int i_l = t & 127, mh = t >> 7;
#pragma unroll
    for (int r = 0; r < 8; ++r)
      XT[i_l][mh * 8 + r] = X[(size_t)(mh * 8 + r) * N_ + i0 + i_l];
  }
  __syncthreads();

  float acc[16];
#pragma unroll
  for (int m = 0; m < 16; ++m) acc[m] = 0.f;

#pragma unroll 8
  for (int i = 0; i < ICH; ++i) {
    const float wv = __builtin_nontemporal_load(W + (size_t)(i0 + i) * N_ + j0);
    float xr[16];
    {
      float4 xv;
      xv = *reinterpret_cast<const float4*>(&XT[i][0]);
      xr[0] = xv.x; xr[1] = xv.y; xr[2] = xv.z; xr[3] = xv.w;
      xv = *reinterpret_cast<const float4*>(&XT[i][4]);
      xr[4] = xv.x; xr[5] = xv.y; xr[6] = xv.z; xr[7] = xv.w;
      xv = *reinterpret_cast<const float4*>(&XT[i][8]);
      xr[8] = xv.x; xr[9] = xv.y; xr[10] = xv.z; xr[11] = xv.w;
      xv = *reinterpret_cast<const float4*>(&XT[i][12]);
      xr[12] = xv.x; xr[13] = xv.y; xr[14] = xv.z; xr[15] = xv.w;
    }
#pragma unroll
    for (int m = 0; m < 16; ++m) acc[m] = fmaf(xr[m], wv, acc[m]);
  }

#pragma unroll
  for (int m = 0; m < 16; ++m)
    __builtin_nontemporal_store(acc[m], part + (size_t)((mat * NIC + ic) * M_ + m) * N_ + j0);
}

// ---------------------------------------------------------------------------
// Kernel 2: reduce partials, RMS-norm q/k, relayout. (as r14)
// ---------------------------------------------------------------------------
__global__ __launch_bounds__(256) void k_reduce(const float* __restrict__ part,
                                                float* __restrict__ qkv) {
  const int mat = blockIdx.z, m = blockIdx.y, nc = blockIdx.x;
  const int t = threadIdx.x;
  const int n = nc * 256 + t;

  float s = 0.f;
#pragma unroll
  for (int ic = 0; ic < NIC; ++ic)
    s += __builtin_nontemporal_load(part + (size_t)((mat * NIC + ic) * M_ + m) * N_ + n);

  float ss = s * s;
#pragma unroll
  for (int off = 1; off < 64; off <<= 1) ss += __shfl_xor(ss, off);
  __shared__ float wsum[4];
  const int wave = t >> 6, lane = t & 63;
  if (lane == 0) wsum[wave] = ss;
  __syncthreads();
  const int half = t >> 7;
  const float tot = wsum[half * 2] + wsum[half * 2 + 1];
  const float scale = (mat < 2) ? rsqrtf(tot * (1.0f / 128.0f)) : 1.0f;

  const int h = n >> 7, d = n & 127;
  qkv[(size_t)((mat * H_ + h) * M_ + m) * D_ + d] = s * scale;
}

// ---------------------------------------------------------------------------
// fold8: reduce a[0..7] over the 8 dq-lanes (lane bits 0..2).
// ---------------------------------------------------------------------------
__device__ __forceinline__ float fold8(float a[8], int dq) {
#pragma unroll
  for (int i = 0; i < 4; ++i) {
    const float send = (dq & 4) ? a[i] : a[i + 4];
    const float recv = __shfl_xor(send, 4);
    a[i] = ((dq & 4) ? a[i + 4] : a[i]) + recv;
  }
#pragma unroll
  for (int i = 0; i < 2; ++i) {
    const float send = (dq & 2) ? a[i] : a[i + 2];
    const float recv = __shfl_xor(send, 2);
    a[i] = ((dq & 2) ? a[i + 2] : a[i]) + recv;
  }
  {
    const float send = (dq & 1) ? a[0] : a[1];
    const float recv = __shfl_xor(send, 1);
    a[0] = ((dq & 1) ? a[1] : a[0]) + recv;
  }
  return a[0];
}

__device__ __forceinline__ unsigned pk2(float a, float b) {
  __hip_bfloat16 ha = __float2bfloat16(a), hb = __float2bfloat16(b);
  const unsigned short ua = *reinterpret_cast<unsigned short*>(&ha);
  const unsigned short ub = *reinterpret_cast<unsigned short*>(&hb);
  return (unsigned)ua | ((unsigned)ub << 16);
}

// ---------------------------------------------------------------------------
// Kernel 3: p-split attention with a 2-DEEP register pipeline (MLP test).
// Identical arithmetic to r14 (passed). Cache chunks (valid=64, 4 batches of
// 8 rows per wave) run a fully unrolled pipeline holding BOTH next-batch K
// and V in flight while the current batch computes (24 outstanding loads vs
// ~12) — the one lever not yet cleanly tested (r16 had it but spilled).
// waves_per_eu(1,8): VGPR cap 256 — demand ~130-150, NO spill possible
// (spills, not structure, wrecked r3/r5/r9/r10/r16). Occupancy proven
// irrelevant (r13 20% vs r14 38%: same dur), so the lower wave count is an
// acceptable trade for MLP depth.
// ---------------------------------------------------------------------------
__global__ __attribute__((amdgpu_waves_per_eu(1, 8)))
__launch_bounds__(256) void k_attn(const float* __restrict__ cacheK,
                                   const float* __restrict__ cacheV,
                                   const float* __restrict__ qkv,
                                   __hip_bfloat16* __restrict__ opart,
                                   float* __restrict__ ml) {
  const int c = blockIdx.x, h = blockIdx.y;
  const int t = threadIdx.x;
  const int wave = t >> 6, lane = t & 63;
  const float* __restrict__ Ksrc = (c < NCH)
      ? (cacheK + ((size_t)h * P_ + (size_t)c * CHUNK) * D_)
      : (qkv + (size_t)((1 * H_ + h) * M_) * D_);
  const float* __restrict__ Vsrc = (c < NCH)
      ? (cacheV + ((size_t)h * P_ + (size_t)c * CHUNK) * D_)
      : (qkv + (size_t)((2 * H_ + h) * M_) * D_);

  __shared__ __align__(16) float smem[4096];    // 16 KB: qs[2048] / obuf[4096]
  __shared__ __align__(16) float wx[4 * 128];   // 2 KB wave-private strips
  __shared__ __align__(16) float mlx[4][8][2];  // per-wave (m, l)

  float* qs = smem;                 // [16][128]
  float* wxp = wx + wave * 128;

  // stage q (16x128)
  {
    const float4* src = reinterpret_cast<const float4*>(qkv + (size_t)(h * M_) * D_);
    reinterpret_cast<float4*>(qs)[t] = src[t];
    reinterpret_cast<float4*>(qs)[t + 256] = src[t + 256];
  }
  __syncthreads();

  const int pg = lane >> 3, dq = lane & 7;
  const int dl = lane * 2;
  const int rg = wave >> 1, mbase = (wave & 1) * 8;
  const int rbase = rg * 32;

  float mrun = -3.0e38f, lrun = 0.f;
  float2 o[8];
#pragma unroll
  for (int mi = 0; mi < 8; ++mi) o[mi] = make_float2(0.f, 0.f);

  auto kload = [&](float4 (&kk)[4], int r0) {
    const float* ka = Ksrc + (size_t)(r0 + pg) * D_ + dq * 4;
    kk[0] = *reinterpret_cast<const float4*>(ka);
    kk[1] = *reinterpret_cast<const float4*>(ka + 32);
    kk[2] = *reinterpret_cast<const float4*>(ka + 64);
    kk[3] = *reinterpret_cast<const float4*>(ka + 96);
  };
  auto vload = [&](float2 (&vv)[8], int r0) {
#pragma unroll
    for (int j = 0; j < 8; ++j)
      vv[j] = *reinterpret_cast<const float2*>(Vsrc + (size_t)(r0 + j) * D_ + dl);
  };
  auto body = [&](float4 (&kk)[4], float2 (&vv)[8]) {
    float a[8];
#pragma unroll
    for (int mi = 0; mi < 8; ++mi) {
      const float* qrow = qs + (mbase + mi) * D_ + dq * 4;
      const float4 q0 = *reinterpret_cast<const float4*>(qrow);
      const float4 q1 = *reinterpret_cast<const float4*>(qrow + 32);
      const float4 q2 = *reinterpret_cast<const float4*>(qrow + 64);
      const float4 q3 = *reinterpret_cast<const float4*>(qrow + 96);
      float s;
      s = q0.x * kk[0].x;
      s = fmaf(q0.y, kk[0].y, s); s = fmaf(q0.z, kk[0].z, s); s = fmaf(q0.w, kk[0].w, s);
      s = fmaf(q1.x, kk[1].x, s); s = fmaf(q1.y, kk[1].y, s);
      s = fmaf(q1.z, kk[1].z, s); s = fmaf(q1.w, kk[1].w, s);
      s = fmaf(q2.x, kk[2].x, s); s = fmaf(q2.y, kk[2].y, s);
      s = fmaf(q2.z, kk[2].z, s); s = fmaf(q2.w, kk[2].w, s);
      s = fmaf(q3.x, kk[3].x, s); s = fmaf(q3.y, kk[3].y, s);
      s = fmaf(q3.z, kk[3].z, s); s = fmaf(q3.w, kk[3].w, s);
      a[mi] = s;
    }
    const float sA = fold8(a, dq);
    float tmax = sA;
    tmax = fmaxf(tmax, __shfl_xor(tmax, 8));
    tmax = fmaxf(tmax, __shfl_xor(tmax, 16));
    tmax = fmaxf(tmax, __shfl_xor(tmax, 32));
    const float mnew = fmaxf(mrun, tmax);
    const float fc = __expf(mrun - mnew);
    mrun = mnew;
    const float wA = __expf(sA - mnew);
    float rs = wA;
    rs += __shfl_xor(rs, 8); rs += __shfl_xor(rs, 16); rs += __shfl_xor(rs, 32);
    lrun = lrun * fc + rs;
    wxp[pg * 8 + dq] = wA;
#pragma unroll
    for (int mi = 0; mi < 8; ++mi) {
      const float fcm = __shfl(fc, (lane & 56) | mi);
      o[mi].x *= fcm; o[mi].y *= fcm;
    }
#pragma unroll
    for (int j = 0; j < 8; ++j) {
      const float4 w0 = *reinterpret_cast<const float4*>(&wxp[j * 8]);
      const float4 w1 = *reinterpret_cast<const float4*>(&wxp[j * 8 + 4]);
      const float2 v = vv[j];
#define PVM(i, wc) o[i].x = fmaf(wc, v.x, o[i].x); o[i].y = fmaf(wc, v.y, o[i].y);
      PVM(0, w0.x) PVM(1, w0.y) PVM(2, w0.z) PVM(3, w0.w)
      PVM(4, w1.x) PVM(5, w1.y) PVM(6, w1.z) PVM(7, w1.w)
#undef PVM
    }
  };

  if (c < NCH) {
    // ---- 2-deep pipeline over the 4 batches (valid = 64 always) ----
    float4 kkA[4], kkB[4];
    float2 vvA[8], vvB[8];
    kload(kkA, rbase);      vload(vvA, rbase);
    kload(kkB, rbase + 8);  vload(vvB, rbase + 8);
    body(kkA, vvA);
    kload(kkA, rbase + 16); vload(vvA, rbase + 16);
    body(kkB, vvB);
    kload(kkB, rbase + 24); vload(vvB, rbase + 24);
    body(kkA, vvA);
    body(kkB, vvB);
  } else {
    // ---- tail chunk (valid = 16): generic r14 loop ----
    int rc = M_ - rbase; rc = (rc < 0) ? 0 : rc;
    const int nb = rc >> 3;   // 2 for waves rg=0, 0 for rg=1
#pragma unroll 1
    for (int b = 0; b < nb; ++b) {
      const int r0 = rbase + b * 8;
      float4 kk[4];
      float2 vv[8];
      kload(kk, r0);
      vload(vv, r0);
      body(kk, vv);
    }
  }

  // ---- merge the 4 wave-partials (obuf aliases dead qs region) ----
  __syncthreads();
  float* obuf = smem;  // [4 waves][8 m][128 d]
#pragma unroll
  for (int mi = 0; mi < 8; ++mi)
    *reinterpret_cast<float2*>(&obuf[wave * 1024 + mi * 128 + dl]) = o[mi];
  if (lane < 8) { mlx[wave][lane][0] = mrun; mlx[wave][lane][1] = lrun; }
  __syncthreads();

  {
    const int mm = t >> 4, seg = t & 15;    // 16 m x 16 segments of 8 d
    const int mh = mm >> 3, mi = mm & 7;    // partials live in waves mh and 2+mh
    const float m0v = mlx[mh][mi][0], m1v = mlx[2 + mh][mi][0];
    const float mstar = fmaxf(m0v, m1v);
    const float e0 = __expf(m0v - mstar), e1 = __expf(m1v - mstar);
    const float T = mlx[mh][mi][1] * e0 + mlx[2 + mh][mi][1] * e1;
    const float4 a0 = *reinterpret_cast<const float4*>(&obuf[mh * 1024 + mi * 128 + seg * 8]);
    const float4 a1 = *reinterpret_cast<const float4*>(&obuf[mh * 1024 + mi * 128 + seg * 8 + 4]);
    const float4 b0 = *reinterpret_cast<const float4*>(&obuf[(2 + mh) * 1024 + mi * 128 + seg * 8]);
    const float4 b1 = *reinterpret_cast<const float4*>(&obuf[(2 + mh) * 1024 + mi * 128 + seg * 8 + 4]);
    float r0 = e0 * a0.x + e1 * b0.x, r1 = e0 * a0.y + e1 * b0.y;
    float r2 = e0 * a0.z + e1 * b0.z, r3 = e0 * a0.w + e1 * b0.w;
    float r4 = e0 * a1.x + e1 * b1.x, r5 = e0 * a1.y + e1 * b1.y;
    float r6 = e0 * a1.z + e1 * b1.z, r7 = e0 * a1.w + e1 * b1.w;
    uint4 pk;
    pk.x = pk2(r0, r1); pk.y = pk2(r2, r3); pk.z = pk2(r4, r5); pk.w = pk2(r6, r7);
    const size_t base = ((size_t)(h * NCH1 + c) * M_ + mm) * D_ + seg * 8;
    *reinterpret_cast<uint4*>(opart + base) = pk;
    if (seg == 0) {
      ml[((size_t)(h * NCH1 + c) * M_ + mm) * 2 + 0] = mstar;
      ml[((size_t)(h * NCH1 + c) * M_ + mm) * 2 + 1] = T;
    }
  }
}

// ---------------------------------------------------------------------------
// Kernel 4: combine 129 chunk partials per (h, m). grid (M_, H_), block 128.
// ---------------------------------------------------------------------------
__global__ __launch_bounds__(128) void k_comb(const __hip_bfloat16* __restrict__ opart,
                                              const float* __restrict__ ml,
                                              float* __restrict__ out) {
  const int m = blockIdx.x, h = blockIdx.y, t = threadIdx.x;
  __shared__ float Ms[NCH1], Ls[NCH1];
  for (int i = t; i < NCH1; i += 128) {
    Ms[i] = ml[((size_t)(h * NCH1 + i) * M_ + m) * 2 + 0];
    Ls[i] = ml[((size_t)(h * NCH1 + i) * M_ + m) * 2 + 1];
  }
  __syncthreads();
  float gM = -3.0e38f;
#pragma unroll 8
  for (int c2 = 0; c2 < NCH1; ++c2) gM = fmaxf(gM, Ms[c2]);

  const __hip_bfloat16* __restrict__ ob =
      opart + (size_t)h * NCH1 * M_ * D_ + (size_t)m * D_ + t;
  float T = 0.f, o0 = 0.f, o1 = 0.f, o2 = 0.f, o3 = 0.f;
#pragma unroll 4
  for (int c2 = 0; c2 < NCH1 - 1; c2 += 4) {
    const float f0 = __expf(Ms[c2 + 0] - gM);
    const float f1 = __expf(Ms[c2 + 1] - gM);
    const float f2 = __expf(Ms[c2 + 2] - gM);
    const float f3 = __expf(Ms[c2 + 3] - gM);
    T = fmaf(Ls[c2 + 0], f0, T); T = fmaf(Ls[c2 + 1], f1, T);
    T = fmaf(Ls[c2 + 2], f2, T); T = fmaf(Ls[c2 + 3], f3, T);
    o0 = fmaf(__bfloat162float(ob[(size_t)(c2 + 0) * M_ * D_]), f0, o0);
    o1 = fmaf(__bfloat162float(ob[(size_t)(c2 + 1) * M_ * D_]), f1, o1);
    o2 = fmaf(__bfloat162float(ob[(size_t)(c2 + 2) * M_ * D_]), f2, o2);
    o3 = fmaf(__bfloat162float(ob[(size_t)(c2 + 3) * M_ * D_]), f3, o3);
  }
  {
    const int c2 = NCH1 - 1;
    const float f = __expf(Ms[c2] - gM);
    T = fmaf(Ls[c2], f, T);
    o0 = fmaf(__bfloat162float(ob[(size_t)c2 * M_ * D_]), f, o0);
  }
  out[(size_t)m * N_ + h * D_ + t] = (o0 + o1 + o2 + o3) / T;
}

// ---------------------------------------------------------------------------
extern "C" void kernel_launch(void* const* d_in, const int* in_sizes, int n_in,
                              void* d_out, int out_size, void* d_ws, size_t ws_size,
                              hipStream_t stream) {
  const float* X  = (const float*)d_in[0];
  const float* Wq = (const float*)d_in[1];
  const float* Wk = (const float*)d_in[2];
  const float* Wv = (const float*)d_in[3];
  const float* cK = (const float*)d_in[4];
  const float* cV = (const float*)d_in[5];
  float* ws    = (float*)d_ws;
  float* qkv   = ws;
  float* part  = ws + PART_OFF;
  __hip_bfloat16* opart = (__hip_bfloat16*)(ws + OPART_OFF);
  float* mlbuf = ws + ML_OFF;
  float* out   = (float*)d_out;

  hipLaunchKernelGGL(k_proj,   dim3(NCB, NIC, 3), dim3(256), 0, stream, X, Wq, Wk, Wv, part);
  hipLaunchKernelGGL(k_reduce, dim3(16, M_, 3),   dim3(256), 0, stream, part, qkv);
  hipLaunchKernelGGL(k_attn,   dim3(NCH1, H_),    dim3(256), 0, stream, cK, cV, qkv, opart, mlbuf);
  hipLaunchKernelGGL(k_comb,   dim3(M_, H_),      dim3(128), 0, stream, opart, mlbuf, out);
}